// Round 8
// baseline (234.707 us; speedup 1.0000x reference)
//
#include <hip/hip_runtime.h>
#include <cstdint>

#define EPS 1e-5f
#define BB   8
#define CIN  384
#define HWs  4096
#define LT   32768
#define DD   128
#define NN   512
#define TOPK 81
#define PSTR 528   // plds row stride in shorts (16B-aligned, conflict-reduced)

typedef short short8 __attribute__((ext_vector_type(8)));   // 8 bf16 (4 VGPRs)
typedef float f32x4  __attribute__((ext_vector_type(4)));

__device__ __forceinline__ unsigned short f2bf(float x) {   // RNE, finite inputs
  unsigned u = __float_as_uint(x);
  u += 0x7fffu + ((u >> 16) & 1u);
  return (unsigned short)(u >> 16);
}
__device__ __forceinline__ float bf2f(unsigned u16) {
  return __uint_as_float(u16 << 16);
}
// write element (row rc in tile, k) of an operand as hi/lo bf16 in MFMA frag order.
// frag layout (HW-verified R1-R3): lane=((k>>3)&3)*16 + rc, j=k&7.
__device__ __forceinline__ void put_frag(unsigned short* buf, int tile, int rc, int k, float v) {
  int ks = k >> 5, g = (k >> 3) & 3, j = k & 7;
  int basehw = ((tile * 4 + ks) * 2) * 512 + (g * 16 + rc) * 8 + j;
  unsigned short hi = f2bf(v);
  buf[basehw] = hi;
  buf[basehw + 512] = f2bf(v - bf2f(hi));
}

// ---------------- prep device bodies ----------------
__device__ __forceinline__ void dr_body(int n, int lane, const float* __restrict__ DR,
    const float* __restrict__ w2, const float* __restrict__ b2,
    const float* __restrict__ w1, const float* __restrict__ b1,
    unsigned short* __restrict__ drwF, unsigned short* __restrict__ drlnF,
    float* __restrict__ t2, float* __restrict__ rcr) {
  const float* row = DR + n * DD;
  float x0 = row[lane], x1 = row[lane + 64];
  float s = x0 + x1, sq = x0 * x0 + x1 * x1;
  #pragma unroll
  for (int o = 32; o; o >>= 1) { s += __shfl_xor(s, o); sq += __shfl_xor(sq, o); }
  float m = s * (1.f / 128.f);
  float v = sq * (1.f / 128.f) - m * m;
  float inv = rsqrtf(v + EPS);
  float y0 = (x0 - m) * inv * w2[lane] + b2[lane];
  float y1 = (x1 - m) * inv * w2[lane + 64] + b2[lane + 64];
  // drwF: B-frag col=n, k=d (nkt=4)
  int nt = n >> 4, cc = n & 15;
  put_frag(drwF, nt, cc, lane, y0 * w1[lane]);
  put_frag(drwF, nt, cc, lane + 64, y1 * w1[lane + 64]);
  // drlnF: B-frag col=d, k=n (nkt=16)
  int ks = n >> 5, gB = (n >> 3) & 3, j = n & 7;
  {
    int d = lane;
    unsigned short hi = f2bf(y0);
    int base = (((d >> 4) * 16 + ks) * 2) * 512 + (gB * 16 + (d & 15)) * 8 + j;
    drlnF[base] = hi;
    drlnF[base + 512] = f2bf(y0 - bf2f(hi));
  }
  {
    int d = lane + 64;
    unsigned short hi = f2bf(y1);
    int base = (((d >> 4) * 16 + ks) * 2) * 512 + (gB * 16 + (d & 15)) * 8 + j;
    drlnF[base] = hi;
    drlnF[base + 512] = f2bf(y1 - bf2f(hi));
  }
  float pt2 = y0 * b1[lane] + y1 * b1[lane + 64];
  float pss = y0 * y0 + y1 * y1;
  #pragma unroll
  for (int o = 32; o; o >>= 1) { pt2 += __shfl_xor(pt2, o); pss += __shfl_xor(pss, o); }
  if (lane == 0) { t2[n] = pt2; rcr[n] = rsqrtf(pss); }
}

__device__ __forceinline__ void bprep_body(const float* __restrict__ src,
    unsigned short* __restrict__ dst, int K, int rt, int kb, int t) {
  int m = t >> 4, kg = t & 15;
  int k0 = kb * 128 + kg * 8;
  const float* s = src + (size_t)(rt * 16 + m) * K + k0;
  float4 f0 = *(const float4*)s;
  float4 f1 = *(const float4*)(s + 4);
  float vs[8] = {f0.x, f0.y, f0.z, f0.w, f1.x, f1.y, f1.z, f1.w};
  short8 hi, lo;
  #pragma unroll
  for (int j = 0; j < 8; ++j) {
    unsigned short h = f2bf(vs[j]);
    hi[j] = (short)h;
    lo[j] = (short)f2bf(vs[j] - bf2f(h));
  }
  int nkt = K >> 5;
  int ks = k0 >> 5, g = (k0 >> 3) & 3;
  short8* D8 = (short8*)dst;
  int base = ((rt * nkt + ks) * 2) * 64 + g * 16 + m;
  D8[base] = hi;
  D8[base + 64] = lo;
}

// ---------------- K_PREP: k_dr (blocks 0..127, 4 n/block) + 3x bprep in ONE launch ----
__global__ __launch_bounds__(256) void k_prep(const float* __restrict__ DR,
    const float* __restrict__ n2w, const float* __restrict__ n2b,
    const float* __restrict__ n1w, const float* __restrict__ n1b,
    unsigned short* __restrict__ drwF, unsigned short* __restrict__ drlnF,
    float* __restrict__ t2, float* __restrict__ rcr,
    const float* __restrict__ win, unsigned short* __restrict__ WinF,
    const float* __restrict__ sw, unsigned short* __restrict__ semWF,
    const float* __restrict__ wout, unsigned short* __restrict__ WoF) {
  int blk = blockIdx.x, t = threadIdx.x;
  if (blk < 128) {
    // DR layernorm prep: wave w handles n = blk*4 + w (all reductions wave-local)
    dr_body(blk * 4 + (t >> 6), t & 63, DR, n2w, n2b, n1w, n1b, drwF, drlnF, t2, rcr);
  } else if (blk < 152) {
    int idx = blk - 128;                       // Win [128,384]: rt 0..7, kb 0..2
    bprep_body(win, WinF, CIN, idx & 7, idx >> 3, t);
  } else if (blk < 160) {
    bprep_body(sw, semWF, DD, blk - 152, 0, t);   // semW [128,128]
  } else {
    bprep_body(wout, WoF, DD, blk - 160, 0, t);   // Wo [384,128]
  }
}

// ---------------- K1+K2 fused: conv_in (384->128) + sem conv (128->128) + LN1 + LN-fold ----
__global__ __launch_bounds__(256, 3) void k_convsem(const float* __restrict__ x,
    const unsigned short* __restrict__ WinF, const float* __restrict__ bin,
    const unsigned short* __restrict__ semWF, const float* __restrict__ sb,
    const float* __restrict__ w1, const float* __restrict__ b1,
    unsigned short* __restrict__ ApF, float* __restrict__ rclv) {
  __shared__ float xt[CIN * 33];
  __shared__ float sredS[32][4], sredQ[32][4];
  __shared__ float rowM[32], rowI[32];
  int t = threadIdx.x;
  int w = t >> 6, lane = t & 63, m = lane & 15, g = lane >> 4;
  int l0 = blockIdx.x * 32;
  int b = l0 >> 12, hw0 = l0 & 4095;
  // ---- phase1a: one-shot x tile staging ----
  {
    const float* xs = x + (size_t)b * CIN * HWs + (size_t)(t >> 3) * HWs + hw0 + (t & 7) * 4;
    float4 v[12];
    #pragma unroll
    for (int r = 0; r < 12; ++r)
      v[r] = *(const float4*)(xs + (size_t)(r * 32) * HWs);
    #pragma unroll
    for (int r = 0; r < 12; ++r) {
      float* d = &xt[(r * 32 + (t >> 3)) * 33 + (t & 7) * 4];
      d[0] = v[r].x; d[1] = v[r].y; d[2] = v[r].z; d[3] = v[r].w;
    }
  }
  __syncthreads();
  // ---- phase1b: conv_in GEMM from LDS ----
  const short8* B8 = (const short8*)WinF;
  f32x4 acc[2][2];
  #pragma unroll
  for (int lt = 0; lt < 2; ++lt)
    #pragma unroll
    for (int j2 = 0; j2 < 2; ++j2) acc[lt][j2] = (f32x4){0.f, 0.f, 0.f, 0.f};
  for (int ks = 0; ks < 12; ++ks) {
    short8 ah[2], al[2];
    #pragma unroll
    for (int lt = 0; lt < 2; ++lt) {
      #pragma unroll
      for (int j = 0; j < 8; ++j) {
        float xv = xt[(ks * 32 + g * 8 + j) * 33 + lt * 16 + m];
        unsigned short h = f2bf(xv);
        ah[lt][j] = (short)h;
        al[lt][j] = (short)f2bf(xv - bf2f(h));
      }
    }
    #pragma unroll
    for (int j2 = 0; j2 < 2; ++j2) {
      int dt = w * 2 + j2;
      short8 bh = B8[((dt * 12 + ks) * 2 + 0) * 64 + lane];
      short8 bl = B8[((dt * 12 + ks) * 2 + 1) * 64 + lane];
      #pragma unroll
      for (int lt = 0; lt < 2; ++lt) {
        acc[lt][j2] = __builtin_amdgcn_mfma_f32_16x16x32_bf16(ah[lt], bh, acc[lt][j2], 0, 0, 0);
        acc[lt][j2] = __builtin_amdgcn_mfma_f32_16x16x32_bf16(ah[lt], bl, acc[lt][j2], 0, 0, 0);
        acc[lt][j2] = __builtin_amdgcn_mfma_f32_16x16x32_bf16(al[lt], bh, acc[lt][j2], 0, 0, 0);
      }
    }
  }
  __syncthreads();   // xt re-used as plane below
  unsigned int* plane = (unsigned int*)xt;
  {
    float bia[2] = {bin[w * 32 + m], bin[w * 32 + 16 + m]};
    #pragma unroll
    for (int lt = 0; lt < 2; ++lt)
      #pragma unroll
      for (int j2 = 0; j2 < 2; ++j2)
        #pragma unroll
        for (int r = 0; r < 4; ++r) {
          float v = acc[lt][j2][r] + bia[j2];
          unsigned short h = f2bf(v);
          unsigned short lo = f2bf(v - bf2f(h));
          plane[(lt * 16 + g * 4 + r) * 132 + (w * 2 + j2) * 16 + m] =
              (unsigned)h | ((unsigned)lo << 16);
        }
  }
  __syncthreads();
  // ---- phase2: sem GEMM, A-frags from LDS ----
  const short8* S8 = (const short8*)semWF;
  f32x4 acc2[2][2];
  #pragma unroll
  for (int lt = 0; lt < 2; ++lt)
    #pragma unroll
    for (int j2 = 0; j2 < 2; ++j2) acc2[lt][j2] = (f32x4){0.f, 0.f, 0.f, 0.f};
  #pragma unroll
  for (int ks2 = 0; ks2 < 4; ++ks2) {
    short8 ah2[2], al2[2];
    #pragma unroll
    for (int lt = 0; lt < 2; ++lt) {
      const unsigned* src = &plane[(lt * 16 + m) * 132 + ks2 * 32 + g * 8];
      uint4 p0 = *(const uint4*)(src);
      uint4 p1 = *(const uint4*)(src + 4);
      unsigned uu[8] = {p0.x, p0.y, p0.z, p0.w, p1.x, p1.y, p1.z, p1.w};
      unsigned* ahp = (unsigned*)&ah2[lt];
      unsigned* alp = (unsigned*)&al2[lt];
      #pragma unroll
      for (int jj = 0; jj < 4; ++jj) {
        unsigned e0 = uu[2 * jj], e1 = uu[2 * jj + 1];
        ahp[jj] = (e0 & 0xffffu) | (e1 << 16);
        alp[jj] = (e0 >> 16) | (e1 & 0xffff0000u);
      }
    }
    #pragma unroll
    for (int j2 = 0; j2 < 2; ++j2) {
      int dt = w * 2 + j2;
      short8 bh = S8[((dt * 4 + ks2) * 2 + 0) * 64 + lane];
      short8 bl = S8[((dt * 4 + ks2) * 2 + 1) * 64 + lane];
      #pragma unroll
      for (int lt = 0; lt < 2; ++lt) {
        acc2[lt][j2] = __builtin_amdgcn_mfma_f32_16x16x32_bf16(ah2[lt], bh, acc2[lt][j2], 0, 0, 0);
        acc2[lt][j2] = __builtin_amdgcn_mfma_f32_16x16x32_bf16(ah2[lt], bl, acc2[lt][j2], 0, 0, 0);
        acc2[lt][j2] = __builtin_amdgcn_mfma_f32_16x16x32_bf16(al2[lt], bh, acc2[lt][j2], 0, 0, 0);
      }
    }
  }
  {
    float bia2[2] = {sb[w * 32 + m], sb[w * 32 + 16 + m]};
    #pragma unroll
    for (int lt = 0; lt < 2; ++lt)
      #pragma unroll
      for (int j2 = 0; j2 < 2; ++j2)
        #pragma unroll
        for (int r = 0; r < 4; ++r) acc2[lt][j2][r] += bia2[j2];
  }
  // ---- LN1 stats round 1 ----
  float s1[2][4], q1[2][4];
  #pragma unroll
  for (int lt = 0; lt < 2; ++lt)
    #pragma unroll
    for (int r = 0; r < 4; ++r) {
      float a = acc2[lt][0][r], b2v = acc2[lt][1][r];
      s1[lt][r] = a + b2v;
      q1[lt][r] = a * a + b2v * b2v;
    }
  #pragma unroll
  for (int o = 1; o < 16; o <<= 1)
    #pragma unroll
    for (int lt = 0; lt < 2; ++lt)
      #pragma unroll
      for (int r = 0; r < 4; ++r) {
        s1[lt][r] += __shfl_xor(s1[lt][r], o);
        q1[lt][r] += __shfl_xor(q1[lt][r], o);
      }
  if (m == 0) {
    #pragma unroll
    for (int lt = 0; lt < 2; ++lt)
      #pragma unroll
      for (int r = 0; r < 4; ++r) {
        sredS[lt * 16 + g * 4 + r][w] = s1[lt][r];
        sredQ[lt * 16 + g * 4 + r][w] = q1[lt][r];
      }
  }
  __syncthreads();
  if (t < 32) {
    float S = sredS[t][0] + sredS[t][1] + sredS[t][2] + sredS[t][3];
    float Q = sredQ[t][0] + sredQ[t][1] + sredQ[t][2] + sredQ[t][3];
    float mu = S * (1.f / 128.f);
    float var = Q * (1.f / 128.f) - mu * mu;
    rowM[t] = mu;
    rowI[t] = rsqrtf(var + EPS);
  }
  __syncthreads();
  float w1v[2] = {w1[w * 32 + m], w1[w * 32 + 16 + m]};
  float b1v[2] = {b1[w * 32 + m], b1[w * 32 + 16 + m]};
  #pragma unroll
  for (int lt = 0; lt < 2; ++lt)
    #pragma unroll
    for (int r = 0; r < 4; ++r) {
      float mu = rowM[lt * 16 + g * 4 + r];
      float iv = rowI[lt * 16 + g * 4 + r];
      float y0 = (acc2[lt][0][r] - mu) * iv * w1v[0] + b1v[0];
      float y1 = (acc2[lt][1][r] - mu) * iv * w1v[1] + b1v[1];
      acc2[lt][0][r] = y0; acc2[lt][1][r] = y1;
      s1[lt][r] = y0 + y1;
      q1[lt][r] = y0 * y0 + y1 * y1;
    }
  #pragma unroll
  for (int o = 1; o < 16; o <<= 1)
    #pragma unroll
    for (int lt = 0; lt < 2; ++lt)
      #pragma unroll
      for (int r = 0; r < 4; ++r) {
        s1[lt][r] += __shfl_xor(s1[lt][r], o);
        q1[lt][r] += __shfl_xor(q1[lt][r], o);
      }
  if (m == 0) {
    #pragma unroll
    for (int lt = 0; lt < 2; ++lt)
      #pragma unroll
      for (int r = 0; r < 4; ++r) {
        sredS[lt * 16 + g * 4 + r][w] = s1[lt][r];
        sredQ[lt * 16 + g * 4 + r][w] = q1[lt][r];
      }
  }
  __syncthreads();
  if (t < 32) {
    float S = sredS[t][0] + sredS[t][1] + sredS[t][2] + sredS[t][3];
    float Q = sredQ[t][0] + sredQ[t][1] + sredQ[t][2] + sredQ[t][3];
    float m2 = S * (1.f / 128.f);
    float v2 = Q * (1.f / 128.f) - m2 * m2;
    float inv2 = rsqrtf(v2 + EPS);
    float rcl = rsqrtf(Q);
    rowM[t] = m2;
    rowI[t] = inv2 * rcl;
    rclv[l0 + t] = rcl;
  }
  __syncthreads();
  // ---- phase3: normalized values -> f32 LDS -> ApF frag pack ----
  float* planef = (float*)xt;
  #pragma unroll
  for (int lt = 0; lt < 2; ++lt)
    #pragma unroll
    for (int r = 0; r < 4; ++r) {
      float m2 = rowM[lt * 16 + g * 4 + r];
      float sc = rowI[lt * 16 + g * 4 + r];
      planef[(lt * 16 + g * 4 + r) * 132 + w * 32 + m] = (acc2[lt][0][r] - m2) * sc;
      planef[(lt * 16 + g * 4 + r) * 132 + w * 32 + 16 + m] = (acc2[lt][1][r] - m2) * sc;
    }
  __syncthreads();
  short8* O8 = (short8*)ApF;
  #pragma unroll
  for (int it = 0; it < 2; ++it) {
    int idx = it * 256 + t;
    int l = idx & 31, dq = idx >> 5;
    const float* src = &planef[l * 132 + dq * 8];
    float4 f0 = *(const float4*)src;
    float4 f1 = *(const float4*)(src + 4);
    float vs[8] = {f0.x, f0.y, f0.z, f0.w, f1.x, f1.y, f1.z, f1.w};
    short8 hi, lo;
    #pragma unroll
    for (int j = 0; j < 8; ++j) {
      unsigned short h = f2bf(vs[j]);
      hi[j] = (short)h;
      lo[j] = (short)f2bf(vs[j] - bf2f(h));
    }
    int ltg = (l0 + l) >> 4;
    int idx8 = ((ltg * 4 + (dq >> 2)) * 2) * 64 + (dq & 3) * 16 + (l & 15);
    O8[idx8] = hi;
    O8[idx8 + 64] = lo;
  }
}

// ---------------- K3 fused: scores+softmax + degrad + conv_out ----------------
// P stays in LDS; pF is GONE (gather recomputes its 5184 rows). Stores per-row
// softmax max (mfv) + 1/denominator (maxv) so the recompute matches.
__global__ __launch_bounds__(256, 4) void k_sdeg(const unsigned short* __restrict__ ApF,
    const unsigned short* __restrict__ drwF, const float* __restrict__ t2g,
    const float* __restrict__ rcrg, const float* __restrict__ rclg,
    const unsigned short* __restrict__ drlnF, const unsigned short* __restrict__ WoF,
    const float* __restrict__ bo,
    float* __restrict__ mfv, float* __restrict__ maxv,
    float* __restrict__ out_img) {
  __shared__ __align__(16) float sredM[32][4];
  __shared__ __align__(16) float sredS[32][4];
  __shared__ __align__(16) unsigned short plds[32 * PSTR];  // 33.8 KB
  int t = threadIdx.x;
  int w = t >> 6, lane = t & 63, c = lane & 15, g = lane >> 4;
  int l0 = blockIdx.x * 32;
  int lt0 = blockIdx.x * 2;
  const short8* A8 = (const short8*)ApF;
  const short8* B8 = (const short8*)drwF;
  // ---- phase A: scores MFMA ----
  f32x4 acc[2][8];
  #pragma unroll
  for (int il = 0; il < 2; ++il)
    #pragma unroll
    for (int jn = 0; jn < 8; ++jn) acc[il][jn] = (f32x4){0.f, 0.f, 0.f, 0.f};
  #pragma unroll
  for (int ks = 0; ks < 4; ++ks) {
    short8 ah0 = A8[((lt0 * 4 + ks) * 2 + 0) * 64 + lane];
    short8 al0 = A8[((lt0 * 4 + ks) * 2 + 1) * 64 + lane];
    short8 ah1 = A8[(((lt0 + 1) * 4 + ks) * 2 + 0) * 64 + lane];
    short8 al1 = A8[(((lt0 + 1) * 4 + ks) * 2 + 1) * 64 + lane];
    #pragma unroll
    for (int jn = 0; jn < 8; ++jn) {
      int nt = w * 8 + jn;
      short8 bh = B8[((nt * 4 + ks) * 2 + 0) * 64 + lane];
      short8 bl = B8[((nt * 4 + ks) * 2 + 1) * 64 + lane];
      acc[0][jn] = __builtin_amdgcn_mfma_f32_16x16x32_bf16(ah0, bh, acc[0][jn], 0, 0, 0);
      acc[0][jn] = __builtin_amdgcn_mfma_f32_16x16x32_bf16(ah0, bl, acc[0][jn], 0, 0, 0);
      acc[0][jn] = __builtin_amdgcn_mfma_f32_16x16x32_bf16(al0, bh, acc[0][jn], 0, 0, 0);
      acc[1][jn] = __builtin_amdgcn_mfma_f32_16x16x32_bf16(ah1, bh, acc[1][jn], 0, 0, 0);
      acc[1][jn] = __builtin_amdgcn_mfma_f32_16x16x32_bf16(ah1, bl, acc[1][jn], 0, 0, 0);
      acc[1][jn] = __builtin_amdgcn_mfma_f32_16x16x32_bf16(al1, bh, acc[1][jn], 0, 0, 0);
    }
  }
  float rcrv[8], t2v[8];
  #pragma unroll
  for (int jn = 0; jn < 8; ++jn) {
    int n = w * 128 + jn * 16 + c;
    rcrv[jn] = rcrg[n]; t2v[jn] = t2g[n];
  }
  float rclr[2][4];
  #pragma unroll
  for (int il = 0; il < 2; ++il)
    #pragma unroll
    for (int r = 0; r < 4; ++r)
      rclr[il][r] = rclg[l0 + il * 16 + g * 4 + r];
  float M[2][4];
  #pragma unroll
  for (int il = 0; il < 2; ++il)
    #pragma unroll
    for (int r = 0; r < 4; ++r) M[il][r] = -1e30f;
  #pragma unroll
  for (int il = 0; il < 2; ++il)
    #pragma unroll
    for (int jn = 0; jn < 8; ++jn) {
      f32x4 a = acc[il][jn];
      #pragma unroll
      for (int r = 0; r < 4; ++r) {
        float s = rcrv[jn] * (a[r] + rclr[il][r] * t2v[jn]);
        a[r] = s;
        M[il][r] = fmaxf(M[il][r], s);
      }
      acc[il][jn] = a;
    }
  #pragma unroll
  for (int o = 1; o < 16; o <<= 1)
    #pragma unroll
    for (int il = 0; il < 2; ++il)
      #pragma unroll
      for (int r = 0; r < 4; ++r)
        M[il][r] = fmaxf(M[il][r], __shfl_xor(M[il][r], o));
  if (c == 0) {
    #pragma unroll
    for (int il = 0; il < 2; ++il)
      #pragma unroll
      for (int r = 0; r < 4; ++r)
        sredM[il * 16 + g * 4 + r][w] = M[il][r];
  }
  __syncthreads();
  float Mf[2][4];
  #pragma unroll
  for (int il = 0; il < 2; ++il)
    #pragma unroll
    for (int r = 0; r < 4; ++r) {
      f32x4 mv = *(const f32x4*)(&sredM[il * 16 + g * 4 + r][0]);
      Mf[il][r] = fmaxf(fmaxf(mv[0], mv[1]), fmaxf(mv[2], mv[3]));
    }
  float S[2][4];
  #pragma unroll
  for (int il = 0; il < 2; ++il)
    #pragma unroll
    for (int r = 0; r < 4; ++r) S[il][r] = 0.f;
  #pragma unroll
  for (int il = 0; il < 2; ++il)
    #pragma unroll
    for (int jn = 0; jn < 8; ++jn) {
      f32x4 a = acc[il][jn];
      #pragma unroll
      for (int r = 0; r < 4; ++r) {
        float e = __expf(a[r] - Mf[il][r]);
        a[r] = e;
        S[il][r] += e;
      }
      acc[il][jn] = a;
    }
  #pragma unroll
  for (int o = 1; o < 16; o <<= 1)
    #pragma unroll
    for (int il = 0; il < 2; ++il)
      #pragma unroll
      for (int r = 0; r < 4; ++r)
        S[il][r] += __shfl_xor(S[il][r], o);
  if (c == 0) {
    #pragma unroll
    for (int il = 0; il < 2; ++il)
      #pragma unroll
      for (int r = 0; r < 4; ++r)
        sredS[il * 16 + g * 4 + r][w] = S[il][r];
  }
  __syncthreads();
  float RS[2][4];
  #pragma unroll
  for (int il = 0; il < 2; ++il)
    #pragma unroll
    for (int r = 0; r < 4; ++r) {
      f32x4 sv = *(const f32x4*)(&sredS[il * 16 + g * 4 + r][0]);
      float tot = sv[0] + sv[1] + sv[2] + sv[3];
      RS[il][r] = 1.f / tot;
    }
  if (w == 0 && c == 0) {
    #pragma unroll
    for (int il = 0; il < 2; ++il)
      #pragma unroll
      for (int r = 0; r < 4; ++r) {
        maxv[l0 + il * 16 + g * 4 + r] = RS[il][r];
        mfv[l0 + il * 16 + g * 4 + r] = Mf[il][r];
      }
  }
  // P -> bf16 -> LDS [row32][col512] (stride PSTR)
  #pragma unroll
  for (int il = 0; il < 2; ++il)
    #pragma unroll
    for (int jn = 0; jn < 8; ++jn)
      #pragma unroll
      for (int r = 0; r < 4; ++r)
        plds[(il * 16 + g * 4 + r) * PSTR + w * 128 + jn * 16 + c] =
            f2bf(acc[il][jn][r] * RS[il][r]);
  __syncthreads();
  // ---- phase B: degrad = P(LDS) @ drln, K=512 ----
  const short8* D8 = (const short8*)drlnF;
  f32x4 accd[2][2];
  #pragma unroll
  for (int lt = 0; lt < 2; ++lt)
    #pragma unroll
    for (int j2 = 0; j2 < 2; ++j2) accd[lt][j2] = (f32x4){0.f, 0.f, 0.f, 0.f};
  for (int ks = 0; ks < 16; ++ks) {
    const unsigned short* sp = &plds[c * PSTR + ks * 32 + g * 8];
    short8 pa0 = *(const short8*)sp;
    short8 pa1 = *(const short8*)(sp + 16 * PSTR);
    #pragma unroll
    for (int j2 = 0; j2 < 2; ++j2) {
      int dt = w * 2 + j2;
      short8 bh = D8[((dt * 16 + ks) * 2 + 0) * 64 + lane];
      short8 bl = D8[((dt * 16 + ks) * 2 + 1) * 64 + lane];
      accd[0][j2] = __builtin_amdgcn_mfma_f32_16x16x32_bf16(pa0, bh, accd[0][j2], 0, 0, 0);
      accd[0][j2] = __builtin_amdgcn_mfma_f32_16x16x32_bf16(pa0, bl, accd[0][j2], 0, 0, 0);
      accd[1][j2] = __builtin_amdgcn_mfma_f32_16x16x32_bf16(pa1, bh, accd[1][j2], 0, 0, 0);
      accd[1][j2] = __builtin_amdgcn_mfma_f32_16x16x32_bf16(pa1, bl, accd[1][j2], 0, 0, 0);
    }
  }
  __syncthreads();   // all plds reads done; reuse as degrad f32 plane
  float* smem2 = (float*)plds;   // [32][132] f32 = 16.9 KB
  #pragma unroll
  for (int lt = 0; lt < 2; ++lt)
    #pragma unroll
    for (int j2 = 0; j2 < 2; ++j2)
      #pragma unroll
      for (int r = 0; r < 4; ++r)
        smem2[(lt * 16 + g * 4 + r) * 132 + w * 32 + j2 * 16 + c] = accd[lt][j2][r];
  __syncthreads();
  // ---- phase C: conv_out = degrad(LDS) @ Wo, K=128 ----
  const short8* W8 = (const short8*)WoF;
  f32x4 acco[2][6];
  #pragma unroll
  for (int lt = 0; lt < 2; ++lt)
    #pragma unroll
    for (int ot = 0; ot < 6; ++ot) acco[lt][ot] = (f32x4){0.f, 0.f, 0.f, 0.f};
  #pragma unroll
  for (int ks2 = 0; ks2 < 4; ++ks2) {
    short8 dh[2];
    #pragma unroll
    for (int lt = 0; lt < 2; ++lt) {
      const float* src = &smem2[(lt * 16 + c) * 132 + ks2 * 32 + g * 8];
      float4 f0 = *(const float4*)src;
      float4 f1 = *(const float4*)(src + 4);
      float vs[8] = {f0.x, f0.y, f0.z, f0.w, f1.x, f1.y, f1.z, f1.w};
      #pragma unroll
      for (int j = 0; j < 8; ++j) dh[lt][j] = (short)f2bf(vs[j]);
    }
    #pragma unroll
    for (int ot = 0; ot < 6; ++ot) {
      int otg = w * 6 + ot;
      short8 wh = W8[((otg * 4 + ks2) * 2 + 0) * 64 + lane];
      short8 wl = W8[((otg * 4 + ks2) * 2 + 1) * 64 + lane];
      #pragma unroll
      for (int lt = 0; lt < 2; ++lt) {
        acco[lt][ot] = __builtin_amdgcn_mfma_f32_16x16x32_bf16(dh[lt], wh, acco[lt][ot], 0, 0, 0);
        acco[lt][ot] = __builtin_amdgcn_mfma_f32_16x16x32_bf16(dh[lt], wl, acco[lt][ot], 0, 0, 0);
      }
    }
  }
  // ---- phase D: direct out_img stores ----
  int b = l0 >> 12, hw0 = l0 & 4095;
  float* ob = out_img + (size_t)b * CIN * HWs + hw0;
  #pragma unroll
  for (int ot = 0; ot < 6; ++ot) {
    float bov = bo[w * 96 + ot * 16 + c];
    #pragma unroll
    for (int lt = 0; lt < 2; ++lt) {
      f32x4 vv = acco[lt][ot];
      float4 o4 = {vv[0] + bov, vv[1] + bov, vv[2] + bov, vv[3] + bov};
      *(float4*)(ob + (size_t)(w * 96 + ot * 16 + c) * HWs + lt * 16 + g * 4) = o4;
    }
  }
}

// ---------------- K5: top-81 via MSB radix-select + fused mask ----------------
// key = (float_bits << 12) | (4095 - idx)  (42 bits; 6 rounds of 8 bits from bit 47)
__global__ __launch_bounds__(256) void k_topk(const float* __restrict__ maxv,
                                              int* __restrict__ tix,
                                              float* __restrict__ outm) {
  __shared__ unsigned int hist[4][256];
  __shared__ unsigned long long slist[TOPK];
  __shared__ unsigned long long bc_prefix;
  __shared__ int bc_need, scount;
  __shared__ float smn[4], smx[4];
  int b = blockIdx.x, t = threadIdx.x;
  int w = t >> 6;
  unsigned long long key[16];
  #pragma unroll
  for (int j = 0; j < 16; ++j) {
    int idx = t + j * 256;
    unsigned int bits = __float_as_uint(maxv[b * HWs + idx]);   // maxv > 0
    key[j] = ((unsigned long long)bits << 12) | (unsigned)(4095 - idx);
  }
  // ---- fused mask: outm = 1 - (rs^3 - mn)/(mx - mn) ----
  {
    float c3[16];
    float mn = 1e30f, mx = -1e30f;
    #pragma unroll
    for (int j = 0; j < 16; ++j) {
      float x = __uint_as_float((unsigned)(key[j] >> 12));
      float cc = x * x * x;
      c3[j] = cc;
      mn = fminf(mn, cc); mx = fmaxf(mx, cc);
    }
    #pragma unroll
    for (int o = 32; o; o >>= 1) { mn = fminf(mn, __shfl_xor(mn, o)); mx = fmaxf(mx, __shfl_xor(mx, o)); }
    if ((t & 63) == 0) { smn[w] = mn; smx[w] = mx; }
    __syncthreads();
    mn = fminf(fminf(smn[0], smn[1]), fminf(smn[2], smn[3]));
    mx = fmaxf(fmaxf(smx[0], smx[1]), fmaxf(smx[2], smx[3]));
    float sc = 1.f / (mx - mn);
    #pragma unroll
    for (int j = 0; j < 16; ++j)
      outm[b * HWs + t + j * 256] = 1.f - (c3[j] - mn) * sc;
  }
  if (t == 0) { bc_prefix = 0ull; bc_need = TOPK; scount = 0; }
  for (int r = 0; r < 6; ++r) {
    int shift = 40 - 8 * r;
    unsigned int* hflat = (unsigned int*)hist;
    hflat[t] = 0; hflat[t + 256] = 0; hflat[t + 512] = 0; hflat[t + 768] = 0;
    __syncthreads();
    unsigned long long prefix = bc_prefix;
    int bins[16];
    #pragma unroll
    for (int j = 0; j < 16; ++j)
      bins[j] = ((key[j] >> (shift + 8)) == prefix) ? (int)((key[j] >> shift) & 255) : -1;
    #pragma unroll
    for (int j = 0; j < 16; ++j) {
      if (bins[j] >= 0) {
        int cnt = 1;
        #pragma unroll
        for (int j2 = j + 1; j2 < 16; ++j2)
          if (bins[j2] == bins[j]) { bins[j2] = -1; ++cnt; }
        atomicAdd(&hist[w][bins[j]], (unsigned)cnt);
      }
    }
    __syncthreads();
    if (t < 64) {   // wave 0: descending scan to locate the boundary bin
      int cb[4], s = 0;
      #pragma unroll
      for (int j = 0; j < 4; ++j) {
        int bin = 255 - (t * 4 + j);
        cb[j] = (int)(hist[0][bin] + hist[1][bin] + hist[2][bin] + hist[3][bin]);
        s += cb[j];
      }
      int P = s;
      #pragma unroll
      for (int o = 1; o < 64; o <<= 1) {
        int u = __shfl_up(P, o);
        if (t >= o) P += u;
      }
      int need = bc_need;
      unsigned long long mask = __ballot(P >= need);
      int first = __ffsll((long long)mask) - 1;
      if (t == first) {
        int acc = P - s;   // candidates in strictly higher bins
        #pragma unroll
        for (int j = 0; j < 4; ++j) {
          if (acc + cb[j] >= need) {
            bc_prefix = (prefix << 8) | (unsigned)(255 - (t * 4 + j));
            bc_need = need - acc;
            break;
          }
          acc += cb[j];
        }
      }
    }
    __syncthreads();
  }
  unsigned long long K81 = bc_prefix;   // exact 81st-largest key
  #pragma unroll
  for (int j = 0; j < 16; ++j)
    if (key[j] >= K81) {
      int pos = atomicAdd(&scount, 1);
      slist[pos] = key[j];
    }
  __syncthreads();
  if (t < TOPK) {
    unsigned long long mine = slist[t];
    int rank = 0;
    for (int i = 0; i < TOPK; ++i) rank += (slist[i] > mine) ? 1 : 0;
    tix[b * TOPK + rank] = 4095 - (int)(mine & 0xFFFull);
  }
}

// ---------------- K6: gather-by-recompute ----------------
// One block per (b2,k): recomputes the selected P row for all 8 batches in f32
// (exact hi+lo dequant of ApF/drwF), using the MFMA-path Mf/RS for consistency.
// Replaces the 33.5 MB pF write with ~0.7 GFLOP of L2-resident math.
__global__ __launch_bounds__(256) void k_gather(const unsigned short* __restrict__ ApF,
    const unsigned short* __restrict__ drwF, const float* __restrict__ t2g,
    const float* __restrict__ rcrg, const float* __restrict__ rclg,
    const float* __restrict__ mfv, const float* __restrict__ rsv,
    const int* __restrict__ tix, float* __restrict__ outr) {
  __shared__ float As[8][128];
  __shared__ float rclS[8], mfS[8], rsS[8];
  int blk = blockIdx.x;
  int k = blk % TOPK, b2 = blk / TOPK;
  int lloc = tix[b2 * TOPK + k];          // hw index within each batch
  int t = threadIdx.x;
  // stage the 8 batches' A rows (dequant hi+lo -> f32), 1024 elems / 256 thr
  {
    int idx = t;
    #pragma unroll
    for (int it = 0; it < 4; ++it, idx += 256) {
      int bb = idx >> 7, d = idx & 127;
      int grow = bb * HWs + lloc;
      int ltg = grow >> 4, mrow = grow & 15;
      int ks = d >> 5, gq = (d >> 3) & 3, j = d & 7;
      int sbase = (((ltg * 4 + ks) * 2) * 64 + gq * 16 + mrow) * 8 + j;
      As[bb][d] = bf2f(ApF[sbase]) + bf2f(ApF[sbase + 512]);
    }
    if (t < 8) {
      int grow = t * HWs + lloc;
      rclS[t] = rclg[grow];
      mfS[t] = mfv[grow];
      rsS[t] = rsv[grow];
    }
  }
  __syncthreads();
  #pragma unroll
  for (int half = 0; half < 2; ++half) {
    int n = half * 256 + t;
    int nt = n >> 4, cc = n & 15;
    float dot[8];
    #pragma unroll
    for (int bb = 0; bb < 8; ++bb) dot[bb] = 0.f;
    #pragma unroll
    for (int d8 = 0; d8 < 16; ++d8) {       // octet d = d8*8 .. d8*8+7
      int ks = d8 >> 2, gq = d8 & 3;
      int sbase = ((nt * 4 + ks) * 2) * 512 + (gq * 16 + cc) * 8;
      const unsigned* hp = (const unsigned*)(drwF + sbase);
      const unsigned* lp = (const unsigned*)(drwF + sbase + 512);
      float bcol[8];
      #pragma unroll
      for (int jj = 0; jj < 4; ++jj) {
        unsigned h2 = hp[jj], l2 = lp[jj];
        bcol[2 * jj]     = bf2f(h2 & 0xffffu) + bf2f(l2 & 0xffffu);
        bcol[2 * jj + 1] = bf2f(h2 >> 16)     + bf2f(l2 >> 16);
      }
      #pragma unroll
      for (int bb = 0; bb < 8; ++bb) {
        #pragma unroll
        for (int j = 0; j < 8; ++j)
          dot[bb] += As[bb][d8 * 8 + j] * bcol[j];
      }
    }
    float rcr = rcrg[n], t2 = t2g[n];
    #pragma unroll
    for (int bb = 0; bb < 8; ++bb) {
      float s = rcr * (dot[bb] + rclS[bb] * t2);
      float p = __expf(s - mfS[bb]) * rsS[bb];
      outr[((size_t)(bb * 8 + b2) * TOPK + k) * NN + n] = p;
    }
  }
}

extern "C" void kernel_launch(void* const* d_in, const int* in_sizes, int n_in,
                              void* d_out, int out_size, void* d_ws, size_t ws_size,
                              hipStream_t stream) {
  const float* x    = (const float*)d_in[0];
  const float* DR   = (const float*)d_in[1];
  const float* win  = (const float*)d_in[2];
  const float* bin  = (const float*)d_in[3];
  const float* sw   = (const float*)d_in[4];
  const float* sb   = (const float*)d_in[5];
  const float* n1w  = (const float*)d_in[6];
  const float* n1b  = (const float*)d_in[7];
  const float* n2w  = (const float*)d_in[8];
  const float* n2b  = (const float*)d_in[9];
  const float* wout = (const float*)d_in[10];
  const float* bout = (const float*)d_in[11];
  float* out = (float*)d_out;
  float* W = (float*)d_ws;

  // workspace layout (float offsets)
  unsigned short* drwF  = (unsigned short*)(W);            // 65536 f
  float* t2   = W + 65536;                                 // 512
  float* rcr  = W + 66048;                                 // 512
  float* rclv = W + 66560;                                 // 32768
  float* maxv = W + 99328;                                 // 32768
  unsigned short* drlnF = (unsigned short*)(W + 132096);   // 65536 f
  unsigned short* WoF   = (unsigned short*)(W + 197632);   // 49152 f
  unsigned short* WinF  = (unsigned short*)(W + 246784);   // 49152 f
  unsigned short* semWF = (unsigned short*)(W + 295936);   // 16384 f
  unsigned short* ApF   = (unsigned short*)(W + 312320);   // 4194304 f
  float* mfv  = W + 4506624;                               // 32768 f (old pF space)
  int*   tix  = (int*)(W + 12895232);                      // 648 ints

  float* out_mask = out;
  float* out_img  = out + 32768;
  float* out_res  = out + 32768 + 12582912;

  k_prep   <<<184, 256, 0, stream>>>(DR, n2w, n2b, n1w, n1b, drwF, drlnF, t2, rcr,
                                     win, WinF, sw, semWF, wout, WoF);
  k_convsem<<<1024, 256, 0, stream>>>(x, WinF, bin, semWF, sb, n1w, n1b, ApF, rclv);
  k_sdeg   <<<1024, 256, 0, stream>>>(ApF, drwF, t2, rcr, rclv, drlnF, WoF, bout,
                                      mfv, maxv, out_img);
  k_topk   <<<BB,   256, 0, stream>>>(maxv, tix, out_mask);
  k_gather <<<BB * TOPK, 256, 0, stream>>>(ApF, drwF, t2, rcr, rclv, mfv, maxv,
                                           tix, out_res);
}

// Round 9
// 210.461 us; speedup vs baseline: 1.1152x; 1.1152x over previous
//
#include <hip/hip_runtime.h>
#include <cstdint>

#define EPS 1e-5f
#define BB   8
#define CIN  384
#define HWs  4096
#define LT   32768
#define DD   128
#define NN   512
#define TOPK 81
#define PSTR 528   // plds row stride in shorts (16B-aligned, conflict-reduced)

typedef short short8 __attribute__((ext_vector_type(8)));   // 8 bf16 (4 VGPRs)
typedef float f32x4  __attribute__((ext_vector_type(4)));

__device__ __forceinline__ unsigned short f2bf(float x) {   // RNE, finite inputs
  unsigned u = __float_as_uint(x);
  u += 0x7fffu + ((u >> 16) & 1u);
  return (unsigned short)(u >> 16);
}
__device__ __forceinline__ float bf2f(unsigned u16) {
  return __uint_as_float(u16 << 16);
}
// write element (row rc in tile, k) of an operand as hi/lo bf16 in MFMA frag order.
// frag layout (HW-verified R1-R3): lane=((k>>3)&3)*16 + rc, j=k&7.
__device__ __forceinline__ void put_frag(unsigned short* buf, int tile, int rc, int k, float v) {
  int ks = k >> 5, g = (k >> 3) & 3, j = k & 7;
  int basehw = ((tile * 4 + ks) * 2) * 512 + (g * 16 + rc) * 8 + j;
  unsigned short hi = f2bf(v);
  buf[basehw] = hi;
  buf[basehw + 512] = f2bf(v - bf2f(hi));
}

// ---------------- prep device bodies ----------------
__device__ __forceinline__ void dr_body(int n, int lane, const float* __restrict__ DR,
    const float* __restrict__ w2, const float* __restrict__ b2,
    const float* __restrict__ w1, const float* __restrict__ b1,
    unsigned short* __restrict__ drwF, unsigned short* __restrict__ drlnF,
    float* __restrict__ t2, float* __restrict__ rcr) {
  const float* row = DR + n * DD;
  float x0 = row[lane], x1 = row[lane + 64];
  float s = x0 + x1, sq = x0 * x0 + x1 * x1;
  #pragma unroll
  for (int o = 32; o; o >>= 1) { s += __shfl_xor(s, o); sq += __shfl_xor(sq, o); }
  float m = s * (1.f / 128.f);
  float v = sq * (1.f / 128.f) - m * m;
  float inv = rsqrtf(v + EPS);
  float y0 = (x0 - m) * inv * w2[lane] + b2[lane];
  float y1 = (x1 - m) * inv * w2[lane + 64] + b2[lane + 64];
  // drwF: B-frag col=n, k=d (nkt=4)
  int nt = n >> 4, cc = n & 15;
  put_frag(drwF, nt, cc, lane, y0 * w1[lane]);
  put_frag(drwF, nt, cc, lane + 64, y1 * w1[lane + 64]);
  // drlnF: B-frag col=d, k=n (nkt=16)
  int ks = n >> 5, gB = (n >> 3) & 3, j = n & 7;
  {
    int d = lane;
    unsigned short hi = f2bf(y0);
    int base = (((d >> 4) * 16 + ks) * 2) * 512 + (gB * 16 + (d & 15)) * 8 + j;
    drlnF[base] = hi;
    drlnF[base + 512] = f2bf(y0 - bf2f(hi));
  }
  {
    int d = lane + 64;
    unsigned short hi = f2bf(y1);
    int base = (((d >> 4) * 16 + ks) * 2) * 512 + (gB * 16 + (d & 15)) * 8 + j;
    drlnF[base] = hi;
    drlnF[base + 512] = f2bf(y1 - bf2f(hi));
  }
  float pt2 = y0 * b1[lane] + y1 * b1[lane + 64];
  float pss = y0 * y0 + y1 * y1;
  #pragma unroll
  for (int o = 32; o; o >>= 1) { pt2 += __shfl_xor(pt2, o); pss += __shfl_xor(pss, o); }
  if (lane == 0) { t2[n] = pt2; rcr[n] = rsqrtf(pss); }
}

__device__ __forceinline__ void bprep_body(const float* __restrict__ src,
    unsigned short* __restrict__ dst, int K, int rt, int kb, int t) {
  int m = t >> 4, kg = t & 15;
  int k0 = kb * 128 + kg * 8;
  const float* s = src + (size_t)(rt * 16 + m) * K + k0;
  float4 f0 = *(const float4*)s;
  float4 f1 = *(const float4*)(s + 4);
  float vs[8] = {f0.x, f0.y, f0.z, f0.w, f1.x, f1.y, f1.z, f1.w};
  short8 hi, lo;
  #pragma unroll
  for (int j = 0; j < 8; ++j) {
    unsigned short h = f2bf(vs[j]);
    hi[j] = (short)h;
    lo[j] = (short)f2bf(vs[j] - bf2f(h));
  }
  int nkt = K >> 5;
  int ks = k0 >> 5, g = (k0 >> 3) & 3;
  short8* D8 = (short8*)dst;
  int base = ((rt * nkt + ks) * 2) * 64 + g * 16 + m;
  D8[base] = hi;
  D8[base + 64] = lo;
}

// ---------------- K_PREP: k_dr (blocks 0..127, 4 n/block) + 3x bprep in ONE launch ----
__global__ __launch_bounds__(256) void k_prep(const float* __restrict__ DR,
    const float* __restrict__ n2w, const float* __restrict__ n2b,
    const float* __restrict__ n1w, const float* __restrict__ n1b,
    unsigned short* __restrict__ drwF, unsigned short* __restrict__ drlnF,
    float* __restrict__ t2, float* __restrict__ rcr,
    const float* __restrict__ win, unsigned short* __restrict__ WinF,
    const float* __restrict__ sw, unsigned short* __restrict__ semWF,
    const float* __restrict__ wout, unsigned short* __restrict__ WoF) {
  int blk = blockIdx.x, t = threadIdx.x;
  if (blk < 128) {
    // DR layernorm prep: wave w handles n = blk*4 + w (all reductions wave-local)
    dr_body(blk * 4 + (t >> 6), t & 63, DR, n2w, n2b, n1w, n1b, drwF, drlnF, t2, rcr);
  } else if (blk < 152) {
    int idx = blk - 128;                       // Win [128,384]: rt 0..7, kb 0..2
    bprep_body(win, WinF, CIN, idx & 7, idx >> 3, t);
  } else if (blk < 160) {
    bprep_body(sw, semWF, DD, blk - 152, 0, t);   // semW [128,128]
  } else {
    bprep_body(wout, WoF, DD, blk - 160, 0, t);   // Wo [384,128]
  }
}

// ---------------- K1+K2 fused: conv_in (384->128) + sem conv (128->128) + LN1 + LN-fold ----
__global__ __launch_bounds__(256, 3) void k_convsem(const float* __restrict__ x,
    const unsigned short* __restrict__ WinF, const float* __restrict__ bin,
    const unsigned short* __restrict__ semWF, const float* __restrict__ sb,
    const float* __restrict__ w1, const float* __restrict__ b1,
    unsigned short* __restrict__ ApF, float* __restrict__ rclv) {
  __shared__ float xt[CIN * 33];
  __shared__ float sredS[32][4], sredQ[32][4];
  __shared__ float rowM[32], rowI[32];
  int t = threadIdx.x;
  int w = t >> 6, lane = t & 63, m = lane & 15, g = lane >> 4;
  int l0 = blockIdx.x * 32;
  int b = l0 >> 12, hw0 = l0 & 4095;
  // ---- phase1a: one-shot x tile staging ----
  {
    const float* xs = x + (size_t)b * CIN * HWs + (size_t)(t >> 3) * HWs + hw0 + (t & 7) * 4;
    float4 v[12];
    #pragma unroll
    for (int r = 0; r < 12; ++r)
      v[r] = *(const float4*)(xs + (size_t)(r * 32) * HWs);
    #pragma unroll
    for (int r = 0; r < 12; ++r) {
      float* d = &xt[(r * 32 + (t >> 3)) * 33 + (t & 7) * 4];
      d[0] = v[r].x; d[1] = v[r].y; d[2] = v[r].z; d[3] = v[r].w;
    }
  }
  __syncthreads();
  // ---- phase1b: conv_in GEMM from LDS ----
  const short8* B8 = (const short8*)WinF;
  f32x4 acc[2][2];
  #pragma unroll
  for (int lt = 0; lt < 2; ++lt)
    #pragma unroll
    for (int j2 = 0; j2 < 2; ++j2) acc[lt][j2] = (f32x4){0.f, 0.f, 0.f, 0.f};
  for (int ks = 0; ks < 12; ++ks) {
    short8 ah[2], al[2];
    #pragma unroll
    for (int lt = 0; lt < 2; ++lt) {
      #pragma unroll
      for (int j = 0; j < 8; ++j) {
        float xv = xt[(ks * 32 + g * 8 + j) * 33 + lt * 16 + m];
        unsigned short h = f2bf(xv);
        ah[lt][j] = (short)h;
        al[lt][j] = (short)f2bf(xv - bf2f(h));
      }
    }
    #pragma unroll
    for (int j2 = 0; j2 < 2; ++j2) {
      int dt = w * 2 + j2;
      short8 bh = B8[((dt * 12 + ks) * 2 + 0) * 64 + lane];
      short8 bl = B8[((dt * 12 + ks) * 2 + 1) * 64 + lane];
      #pragma unroll
      for (int lt = 0; lt < 2; ++lt) {
        acc[lt][j2] = __builtin_amdgcn_mfma_f32_16x16x32_bf16(ah[lt], bh, acc[lt][j2], 0, 0, 0);
        acc[lt][j2] = __builtin_amdgcn_mfma_f32_16x16x32_bf16(ah[lt], bl, acc[lt][j2], 0, 0, 0);
        acc[lt][j2] = __builtin_amdgcn_mfma_f32_16x16x32_bf16(al[lt], bh, acc[lt][j2], 0, 0, 0);
      }
    }
  }
  __syncthreads();   // xt re-used as plane below
  unsigned int* plane = (unsigned int*)xt;
  {
    float bia[2] = {bin[w * 32 + m], bin[w * 32 + 16 + m]};
    #pragma unroll
    for (int lt = 0; lt < 2; ++lt)
      #pragma unroll
      for (int j2 = 0; j2 < 2; ++j2)
        #pragma unroll
        for (int r = 0; r < 4; ++r) {
          float v = acc[lt][j2][r] + bia[j2];
          unsigned short h = f2bf(v);
          unsigned short lo = f2bf(v - bf2f(h));
          plane[(lt * 16 + g * 4 + r) * 132 + (w * 2 + j2) * 16 + m] =
              (unsigned)h | ((unsigned)lo << 16);
        }
  }
  __syncthreads();
  // ---- phase2: sem GEMM, A-frags from LDS ----
  const short8* S8 = (const short8*)semWF;
  f32x4 acc2[2][2];
  #pragma unroll
  for (int lt = 0; lt < 2; ++lt)
    #pragma unroll
    for (int j2 = 0; j2 < 2; ++j2) acc2[lt][j2] = (f32x4){0.f, 0.f, 0.f, 0.f};
  #pragma unroll
  for (int ks2 = 0; ks2 < 4; ++ks2) {
    short8 ah2[2], al2[2];
    #pragma unroll
    for (int lt = 0; lt < 2; ++lt) {
      const unsigned* src = &plane[(lt * 16 + m) * 132 + ks2 * 32 + g * 8];
      uint4 p0 = *(const uint4*)(src);
      uint4 p1 = *(const uint4*)(src + 4);
      unsigned uu[8] = {p0.x, p0.y, p0.z, p0.w, p1.x, p1.y, p1.z, p1.w};
      unsigned* ahp = (unsigned*)&ah2[lt];
      unsigned* alp = (unsigned*)&al2[lt];
      #pragma unroll
      for (int jj = 0; jj < 4; ++jj) {
        unsigned e0 = uu[2 * jj], e1 = uu[2 * jj + 1];
        ahp[jj] = (e0 & 0xffffu) | (e1 << 16);
        alp[jj] = (e0 >> 16) | (e1 & 0xffff0000u);
      }
    }
    #pragma unroll
    for (int j2 = 0; j2 < 2; ++j2) {
      int dt = w * 2 + j2;
      short8 bh = S8[((dt * 4 + ks2) * 2 + 0) * 64 + lane];
      short8 bl = S8[((dt * 4 + ks2) * 2 + 1) * 64 + lane];
      #pragma unroll
      for (int lt = 0; lt < 2; ++lt) {
        acc2[lt][j2] = __builtin_amdgcn_mfma_f32_16x16x32_bf16(ah2[lt], bh, acc2[lt][j2], 0, 0, 0);
        acc2[lt][j2] = __builtin_amdgcn_mfma_f32_16x16x32_bf16(ah2[lt], bl, acc2[lt][j2], 0, 0, 0);
        acc2[lt][j2] = __builtin_amdgcn_mfma_f32_16x16x32_bf16(al2[lt], bh, acc2[lt][j2], 0, 0, 0);
      }
    }
  }
  {
    float bia2[2] = {sb[w * 32 + m], sb[w * 32 + 16 + m]};
    #pragma unroll
    for (int lt = 0; lt < 2; ++lt)
      #pragma unroll
      for (int j2 = 0; j2 < 2; ++j2)
        #pragma unroll
        for (int r = 0; r < 4; ++r) acc2[lt][j2][r] += bia2[j2];
  }
  // ---- LN1 stats round 1 ----
  float s1[2][4], q1[2][4];
  #pragma unroll
  for (int lt = 0; lt < 2; ++lt)
    #pragma unroll
    for (int r = 0; r < 4; ++r) {
      float a = acc2[lt][0][r], b2v = acc2[lt][1][r];
      s1[lt][r] = a + b2v;
      q1[lt][r] = a * a + b2v * b2v;
    }
  #pragma unroll
  for (int o = 1; o < 16; o <<= 1)
    #pragma unroll
    for (int lt = 0; lt < 2; ++lt)
      #pragma unroll
      for (int r = 0; r < 4; ++r) {
        s1[lt][r] += __shfl_xor(s1[lt][r], o);
        q1[lt][r] += __shfl_xor(q1[lt][r], o);
      }
  if (m == 0) {
    #pragma unroll
    for (int lt = 0; lt < 2; ++lt)
      #pragma unroll
      for (int r = 0; r < 4; ++r) {
        sredS[lt * 16 + g * 4 + r][w] = s1[lt][r];
        sredQ[lt * 16 + g * 4 + r][w] = q1[lt][r];
      }
  }
  __syncthreads();
  if (t < 32) {
    float S = sredS[t][0] + sredS[t][1] + sredS[t][2] + sredS[t][3];
    float Q = sredQ[t][0] + sredQ[t][1] + sredQ[t][2] + sredQ[t][3];
    float mu = S * (1.f / 128.f);
    float var = Q * (1.f / 128.f) - mu * mu;
    rowM[t] = mu;
    rowI[t] = rsqrtf(var + EPS);
  }
  __syncthreads();
  float w1v[2] = {w1[w * 32 + m], w1[w * 32 + 16 + m]};
  float b1v[2] = {b1[w * 32 + m], b1[w * 32 + 16 + m]};
  #pragma unroll
  for (int lt = 0; lt < 2; ++lt)
    #pragma unroll
    for (int r = 0; r < 4; ++r) {
      float mu = rowM[lt * 16 + g * 4 + r];
      float iv = rowI[lt * 16 + g * 4 + r];
      float y0 = (acc2[lt][0][r] - mu) * iv * w1v[0] + b1v[0];
      float y1 = (acc2[lt][1][r] - mu) * iv * w1v[1] + b1v[1];
      acc2[lt][0][r] = y0; acc2[lt][1][r] = y1;
      s1[lt][r] = y0 + y1;
      q1[lt][r] = y0 * y0 + y1 * y1;
    }
  #pragma unroll
  for (int o = 1; o < 16; o <<= 1)
    #pragma unroll
    for (int lt = 0; lt < 2; ++lt)
      #pragma unroll
      for (int r = 0; r < 4; ++r) {
        s1[lt][r] += __shfl_xor(s1[lt][r], o);
        q1[lt][r] += __shfl_xor(q1[lt][r], o);
      }
  if (m == 0) {
    #pragma unroll
    for (int lt = 0; lt < 2; ++lt)
      #pragma unroll
      for (int r = 0; r < 4; ++r) {
        sredS[lt * 16 + g * 4 + r][w] = s1[lt][r];
        sredQ[lt * 16 + g * 4 + r][w] = q1[lt][r];
      }
  }
  __syncthreads();
  if (t < 32) {
    float S = sredS[t][0] + sredS[t][1] + sredS[t][2] + sredS[t][3];
    float Q = sredQ[t][0] + sredQ[t][1] + sredQ[t][2] + sredQ[t][3];
    float m2 = S * (1.f / 128.f);
    float v2 = Q * (1.f / 128.f) - m2 * m2;
    float inv2 = rsqrtf(v2 + EPS);
    float rcl = rsqrtf(Q);
    rowM[t] = m2;
    rowI[t] = inv2 * rcl;
    rclv[l0 + t] = rcl;
  }
  __syncthreads();
  // ---- phase3: normalized values -> f32 LDS -> ApF frag pack ----
  float* planef = (float*)xt;
  #pragma unroll
  for (int lt = 0; lt < 2; ++lt)
    #pragma unroll
    for (int r = 0; r < 4; ++r) {
      float m2 = rowM[lt * 16 + g * 4 + r];
      float sc = rowI[lt * 16 + g * 4 + r];
      planef[(lt * 16 + g * 4 + r) * 132 + w * 32 + m] = (acc2[lt][0][r] - m2) * sc;
      planef[(lt * 16 + g * 4 + r) * 132 + w * 32 + 16 + m] = (acc2[lt][1][r] - m2) * sc;
    }
  __syncthreads();
  short8* O8 = (short8*)ApF;
  #pragma unroll
  for (int it = 0; it < 2; ++it) {
    int idx = it * 256 + t;
    int l = idx & 31, dq = idx >> 5;
    const float* src = &planef[l * 132 + dq * 8];
    float4 f0 = *(const float4*)src;
    float4 f1 = *(const float4*)(src + 4);
    float vs[8] = {f0.x, f0.y, f0.z, f0.w, f1.x, f1.y, f1.z, f1.w};
    short8 hi, lo;
    #pragma unroll
    for (int j = 0; j < 8; ++j) {
      unsigned short h = f2bf(vs[j]);
      hi[j] = (short)h;
      lo[j] = (short)f2bf(vs[j] - bf2f(h));
    }
    int ltg = (l0 + l) >> 4;
    int idx8 = ((ltg * 4 + (dq >> 2)) * 2) * 64 + (dq & 3) * 16 + (l & 15);
    O8[idx8] = hi;
    O8[idx8 + 64] = lo;
  }
}

// ---------------- K3 fused: scores+softmax + degrad + conv_out ----------------
// P stays in LDS (never re-read from HBM); pF written for gather only.
// conv_out epilogue: direct float4 stores (plain — NT stores regressed, R7/R8).
__global__ __launch_bounds__(256, 4) void k_sdeg(const unsigned short* __restrict__ ApF,
    const unsigned short* __restrict__ drwF, const float* __restrict__ t2g,
    const float* __restrict__ rcrg, const float* __restrict__ rclg,
    const unsigned short* __restrict__ drlnF, const unsigned short* __restrict__ WoF,
    const float* __restrict__ bo,
    unsigned short* __restrict__ pF, float* __restrict__ maxv,
    float* __restrict__ out_img) {
  __shared__ __align__(16) float sredM[32][4];
  __shared__ __align__(16) float sredS[32][4];
  __shared__ __align__(16) unsigned short plds[32 * PSTR];  // 33.8 KB
  int t = threadIdx.x;
  int w = t >> 6, lane = t & 63, c = lane & 15, g = lane >> 4;
  int l0 = blockIdx.x * 32;
  int lt0 = blockIdx.x * 2;
  const short8* A8 = (const short8*)ApF;
  const short8* B8 = (const short8*)drwF;
  // ---- phase A: scores MFMA ----
  f32x4 acc[2][8];
  #pragma unroll
  for (int il = 0; il < 2; ++il)
    #pragma unroll
    for (int jn = 0; jn < 8; ++jn) acc[il][jn] = (f32x4){0.f, 0.f, 0.f, 0.f};
  #pragma unroll
  for (int ks = 0; ks < 4; ++ks) {
    short8 ah0 = A8[((lt0 * 4 + ks) * 2 + 0) * 64 + lane];
    short8 al0 = A8[((lt0 * 4 + ks) * 2 + 1) * 64 + lane];
    short8 ah1 = A8[(((lt0 + 1) * 4 + ks) * 2 + 0) * 64 + lane];
    short8 al1 = A8[(((lt0 + 1) * 4 + ks) * 2 + 1) * 64 + lane];
    #pragma unroll
    for (int jn = 0; jn < 8; ++jn) {
      int nt = w * 8 + jn;
      short8 bh = B8[((nt * 4 + ks) * 2 + 0) * 64 + lane];
      short8 bl = B8[((nt * 4 + ks) * 2 + 1) * 64 + lane];
      acc[0][jn] = __builtin_amdgcn_mfma_f32_16x16x32_bf16(ah0, bh, acc[0][jn], 0, 0, 0);
      acc[0][jn] = __builtin_amdgcn_mfma_f32_16x16x32_bf16(ah0, bl, acc[0][jn], 0, 0, 0);
      acc[0][jn] = __builtin_amdgcn_mfma_f32_16x16x32_bf16(al0, bh, acc[0][jn], 0, 0, 0);
      acc[1][jn] = __builtin_amdgcn_mfma_f32_16x16x32_bf16(ah1, bh, acc[1][jn], 0, 0, 0);
      acc[1][jn] = __builtin_amdgcn_mfma_f32_16x16x32_bf16(ah1, bl, acc[1][jn], 0, 0, 0);
      acc[1][jn] = __builtin_amdgcn_mfma_f32_16x16x32_bf16(al1, bh, acc[1][jn], 0, 0, 0);
    }
  }
  float rcrv[8], t2v[8];
  #pragma unroll
  for (int jn = 0; jn < 8; ++jn) {
    int n = w * 128 + jn * 16 + c;
    rcrv[jn] = rcrg[n]; t2v[jn] = t2g[n];
  }
  float rclr[2][4];
  #pragma unroll
  for (int il = 0; il < 2; ++il)
    #pragma unroll
    for (int r = 0; r < 4; ++r)
      rclr[il][r] = rclg[l0 + il * 16 + g * 4 + r];
  float M[2][4];
  #pragma unroll
  for (int il = 0; il < 2; ++il)
    #pragma unroll
    for (int r = 0; r < 4; ++r) M[il][r] = -1e30f;
  #pragma unroll
  for (int il = 0; il < 2; ++il)
    #pragma unroll
    for (int jn = 0; jn < 8; ++jn) {
      f32x4 a = acc[il][jn];
      #pragma unroll
      for (int r = 0; r < 4; ++r) {
        float s = rcrv[jn] * (a[r] + rclr[il][r] * t2v[jn]);
        a[r] = s;
        M[il][r] = fmaxf(M[il][r], s);
      }
      acc[il][jn] = a;
    }
  #pragma unroll
  for (int o = 1; o < 16; o <<= 1)
    #pragma unroll
    for (int il = 0; il < 2; ++il)
      #pragma unroll
      for (int r = 0; r < 4; ++r)
        M[il][r] = fmaxf(M[il][r], __shfl_xor(M[il][r], o));
  if (c == 0) {
    #pragma unroll
    for (int il = 0; il < 2; ++il)
      #pragma unroll
      for (int r = 0; r < 4; ++r)
        sredM[il * 16 + g * 4 + r][w] = M[il][r];
  }
  __syncthreads();
  float Mf[2][4];
  #pragma unroll
  for (int il = 0; il < 2; ++il)
    #pragma unroll
    for (int r = 0; r < 4; ++r) {
      f32x4 mv = *(const f32x4*)(&sredM[il * 16 + g * 4 + r][0]);
      Mf[il][r] = fmaxf(fmaxf(mv[0], mv[1]), fmaxf(mv[2], mv[3]));
    }
  float S[2][4];
  #pragma unroll
  for (int il = 0; il < 2; ++il)
    #pragma unroll
    for (int r = 0; r < 4; ++r) S[il][r] = 0.f;
  #pragma unroll
  for (int il = 0; il < 2; ++il)
    #pragma unroll
    for (int jn = 0; jn < 8; ++jn) {
      f32x4 a = acc[il][jn];
      #pragma unroll
      for (int r = 0; r < 4; ++r) {
        float e = __expf(a[r] - Mf[il][r]);
        a[r] = e;
        S[il][r] += e;
      }
      acc[il][jn] = a;
    }
  #pragma unroll
  for (int o = 1; o < 16; o <<= 1)
    #pragma unroll
    for (int il = 0; il < 2; ++il)
      #pragma unroll
      for (int r = 0; r < 4; ++r)
        S[il][r] += __shfl_xor(S[il][r], o);
  if (c == 0) {
    #pragma unroll
    for (int il = 0; il < 2; ++il)
      #pragma unroll
      for (int r = 0; r < 4; ++r)
        sredS[il * 16 + g * 4 + r][w] = S[il][r];
  }
  __syncthreads();
  float RS[2][4];
  #pragma unroll
  for (int il = 0; il < 2; ++il)
    #pragma unroll
    for (int r = 0; r < 4; ++r) {
      f32x4 sv = *(const f32x4*)(&sredS[il * 16 + g * 4 + r][0]);
      float tot = sv[0] + sv[1] + sv[2] + sv[3];
      RS[il][r] = 1.f / tot;
    }
  if (w == 0 && c == 0) {
    #pragma unroll
    for (int il = 0; il < 2; ++il)
      #pragma unroll
      for (int r = 0; r < 4; ++r)
        maxv[l0 + il * 16 + g * 4 + r] = RS[il][r];
  }
  // P -> bf16 -> LDS [row32][col512] (stride PSTR)
  #pragma unroll
  for (int il = 0; il < 2; ++il)
    #pragma unroll
    for (int jn = 0; jn < 8; ++jn)
      #pragma unroll
      for (int r = 0; r < 4; ++r)
        plds[(il * 16 + g * 4 + r) * PSTR + w * 128 + jn * 16 + c] =
            f2bf(acc[il][jn][r] * RS[il][r]);
  __syncthreads();
  // ---- phase B: degrad = P(LDS) @ drln, K=512 ----
  const short8* D8 = (const short8*)drlnF;
  f32x4 accd[2][2];
  #pragma unroll
  for (int lt = 0; lt < 2; ++lt)
    #pragma unroll
    for (int j2 = 0; j2 < 2; ++j2) accd[lt][j2] = (f32x4){0.f, 0.f, 0.f, 0.f};
  for (int ks = 0; ks < 16; ++ks) {
    const unsigned short* sp = &plds[c * PSTR + ks * 32 + g * 8];
    short8 pa0 = *(const short8*)sp;
    short8 pa1 = *(const short8*)(sp + 16 * PSTR);
    #pragma unroll
    for (int j2 = 0; j2 < 2; ++j2) {
      int dt = w * 2 + j2;
      short8 bh = D8[((dt * 16 + ks) * 2 + 0) * 64 + lane];
      short8 bl = D8[((dt * 16 + ks) * 2 + 1) * 64 + lane];
      accd[0][j2] = __builtin_amdgcn_mfma_f32_16x16x32_bf16(pa0, bh, accd[0][j2], 0, 0, 0);
      accd[0][j2] = __builtin_amdgcn_mfma_f32_16x16x32_bf16(pa0, bl, accd[0][j2], 0, 0, 0);
      accd[1][j2] = __builtin_amdgcn_mfma_f32_16x16x32_bf16(pa1, bh, accd[1][j2], 0, 0, 0);
      accd[1][j2] = __builtin_amdgcn_mfma_f32_16x16x32_bf16(pa1, bl, accd[1][j2], 0, 0, 0);
    }
  }
  // pF store for gather (reads plds; before the re-use barrier)
  short8* P8o = (short8*)pF;
  #pragma unroll
  for (int it = 0; it < 8; ++it) {
    int slot = it * 256 + t;               // slot = ltl*1024 + ks*64 + gB*16 + mrow
    int ltl = slot >> 10;
    int ks = (slot >> 6) & 15;
    int gB = (slot >> 4) & 3;
    int mrow = slot & 15;
    int row = ltl * 16 + mrow;
    int n0 = ks * 32 + gB * 8;
    short8 v = *(const short8*)(&plds[row * PSTR + n0]);
    P8o[blockIdx.x * 2048 + slot] = v;
  }
  __syncthreads();   // all plds reads done; reuse as degrad f32 plane
  float* smem2 = (float*)plds;   // [32][132] f32 = 16.9 KB
  #pragma unroll
  for (int lt = 0; lt < 2; ++lt)
    #pragma unroll
    for (int j2 = 0; j2 < 2; ++j2)
      #pragma unroll
      for (int r = 0; r < 4; ++r)
        smem2[(lt * 16 + g * 4 + r) * 132 + w * 32 + j2 * 16 + c] = accd[lt][j2][r];
  __syncthreads();
  // ---- phase C: conv_out = degrad(LDS) @ Wo, K=128 ----
  const short8* W8 = (const short8*)WoF;
  f32x4 acco[2][6];
  #pragma unroll
  for (int lt = 0; lt < 2; ++lt)
    #pragma unroll
    for (int ot = 0; ot < 6; ++ot) acco[lt][ot] = (f32x4){0.f, 0.f, 0.f, 0.f};
  #pragma unroll
  for (int ks2 = 0; ks2 < 4; ++ks2) {
    short8 dh[2];
    #pragma unroll
    for (int lt = 0; lt < 2; ++lt) {
      const float* src = &smem2[(lt * 16 + c) * 132 + ks2 * 32 + g * 8];
      float4 f0 = *(const float4*)src;
      float4 f1 = *(const float4*)(src + 4);
      float vs[8] = {f0.x, f0.y, f0.z, f0.w, f1.x, f1.y, f1.z, f1.w};
      #pragma unroll
      for (int j = 0; j < 8; ++j) dh[lt][j] = (short)f2bf(vs[j]);
    }
    #pragma unroll
    for (int ot = 0; ot < 6; ++ot) {
      int otg = w * 6 + ot;
      short8 wh = W8[((otg * 4 + ks2) * 2 + 0) * 64 + lane];
      short8 wl = W8[((otg * 4 + ks2) * 2 + 1) * 64 + lane];
      #pragma unroll
      for (int lt = 0; lt < 2; ++lt) {
        acco[lt][ot] = __builtin_amdgcn_mfma_f32_16x16x32_bf16(dh[lt], wh, acco[lt][ot], 0, 0, 0);
        acco[lt][ot] = __builtin_amdgcn_mfma_f32_16x16x32_bf16(dh[lt], wl, acco[lt][ot], 0, 0, 0);
      }
    }
  }
  // ---- phase D: direct out_img stores ----
  int b = l0 >> 12, hw0 = l0 & 4095;
  float* ob = out_img + (size_t)b * CIN * HWs + hw0;
  #pragma unroll
  for (int ot = 0; ot < 6; ++ot) {
    float bov = bo[w * 96 + ot * 16 + c];
    #pragma unroll
    for (int lt = 0; lt < 2; ++lt) {
      f32x4 vv = acco[lt][ot];
      float4 o4 = {vv[0] + bov, vv[1] + bov, vv[2] + bov, vv[3] + bov};
      *(float4*)(ob + (size_t)(w * 96 + ot * 16 + c) * HWs + lt * 16 + g * 4) = o4;
    }
  }
}

// ---------------- K5: top-81 via MSB radix-select + fused mask ----------------
// key = (float_bits << 12) | (4095 - idx)  (42 bits; 6 rounds of 8 bits from bit 47)
__global__ __launch_bounds__(256) void k_topk(const float* __restrict__ maxv,
                                              int* __restrict__ tix,
                                              float* __restrict__ outm) {
  __shared__ unsigned int hist[4][256];
  __shared__ unsigned long long slist[TOPK];
  __shared__ unsigned long long bc_prefix;
  __shared__ int bc_need, scount;
  __shared__ float smn[4], smx[4];
  int b = blockIdx.x, t = threadIdx.x;
  int w = t >> 6;
  unsigned long long key[16];
  #pragma unroll
  for (int j = 0; j < 16; ++j) {
    int idx = t + j * 256;
    unsigned int bits = __float_as_uint(maxv[b * HWs + idx]);   // maxv > 0
    key[j] = ((unsigned long long)bits << 12) | (unsigned)(4095 - idx);
  }
  // ---- fused mask: outm = 1 - (rs^3 - mn)/(mx - mn) ----
  {
    float c3[16];
    float mn = 1e30f, mx = -1e30f;
    #pragma unroll
    for (int j = 0; j < 16; ++j) {
      float x = __uint_as_float((unsigned)(key[j] >> 12));
      float cc = x * x * x;
      c3[j] = cc;
      mn = fminf(mn, cc); mx = fmaxf(mx, cc);
    }
    #pragma unroll
    for (int o = 32; o; o >>= 1) { mn = fminf(mn, __shfl_xor(mn, o)); mx = fmaxf(mx, __shfl_xor(mx, o)); }
    if ((t & 63) == 0) { smn[w] = mn; smx[w] = mx; }
    __syncthreads();
    mn = fminf(fminf(smn[0], smn[1]), fminf(smn[2], smn[3]));
    mx = fmaxf(fmaxf(smx[0], smx[1]), fmaxf(smx[2], smx[3]));
    float sc = 1.f / (mx - mn);
    #pragma unroll
    for (int j = 0; j < 16; ++j)
      outm[b * HWs + t + j * 256] = 1.f - (c3[j] - mn) * sc;
  }
  if (t == 0) { bc_prefix = 0ull; bc_need = TOPK; scount = 0; }
  for (int r = 0; r < 6; ++r) {
    int shift = 40 - 8 * r;
    unsigned int* hflat = (unsigned int*)hist;
    hflat[t] = 0; hflat[t + 256] = 0; hflat[t + 512] = 0; hflat[t + 768] = 0;
    __syncthreads();
    unsigned long long prefix = bc_prefix;
    int bins[16];
    #pragma unroll
    for (int j = 0; j < 16; ++j)
      bins[j] = ((key[j] >> (shift + 8)) == prefix) ? (int)((key[j] >> shift) & 255) : -1;
    #pragma unroll
    for (int j = 0; j < 16; ++j) {
      if (bins[j] >= 0) {
        int cnt = 1;
        #pragma unroll
        for (int j2 = j + 1; j2 < 16; ++j2)
          if (bins[j2] == bins[j]) { bins[j2] = -1; ++cnt; }
        atomicAdd(&hist[w][bins[j]], (unsigned)cnt);
      }
    }
    __syncthreads();
    if (t < 64) {   // wave 0: descending scan to locate the boundary bin
      int cb[4], s = 0;
      #pragma unroll
      for (int j = 0; j < 4; ++j) {
        int bin = 255 - (t * 4 + j);
        cb[j] = (int)(hist[0][bin] + hist[1][bin] + hist[2][bin] + hist[3][bin]);
        s += cb[j];
      }
      int P = s;
      #pragma unroll
      for (int o = 1; o < 64; o <<= 1) {
        int u = __shfl_up(P, o);
        if (t >= o) P += u;
      }
      int need = bc_need;
      unsigned long long mask = __ballot(P >= need);
      int first = __ffsll((long long)mask) - 1;
      if (t == first) {
        int acc = P - s;   // candidates in strictly higher bins
        #pragma unroll
        for (int j = 0; j < 4; ++j) {
          if (acc + cb[j] >= need) {
            bc_prefix = (prefix << 8) | (unsigned)(255 - (t * 4 + j));
            bc_need = need - acc;
            break;
          }
          acc += cb[j];
        }
      }
    }
    __syncthreads();
  }
  unsigned long long K81 = bc_prefix;   // exact 81st-largest key
  #pragma unroll
  for (int j = 0; j < 16; ++j)
    if (key[j] >= K81) {
      int pos = atomicAdd(&scount, 1);
      slist[pos] = key[j];
    }
  __syncthreads();
  if (t < TOPK) {
    unsigned long long mine = slist[t];
    int rank = 0;
    for (int i = 0; i < TOPK; ++i) rank += (slist[i] > mine) ? 1 : 0;
    tix[b * TOPK + rank] = 4095 - (int)(mine & 0xFFFull);
  }
}

// ---------------- K6: gather ----------------
__global__ __launch_bounds__(128) void k_gather(const unsigned short* __restrict__ pF,
    const int* __restrict__ tix, float* __restrict__ outr) {
  int gB_ = blockIdx.x;
  int k = gB_ % TOPK;
  int bb = gB_ / TOPK;
  int b2 = bb & 7, b = bb >> 3;
  int l = b * HWs + tix[b2 * TOPK + k];
  int lt = l >> 4, mrow = l & 15;
  int t = threadIdx.x;
  int ks = t >> 3, gq = (t >> 1) & 3, j0 = (t & 1) * 4;
  int base = ((lt * 16 + ks) * 64 + gq * 16 + mrow) * 8 + j0;
  const unsigned* src = (const unsigned*)(pF + base);
  unsigned u0 = src[0], u1 = src[1];
  float4 v = {bf2f(u0 & 0xffffu), bf2f(u0 >> 16), bf2f(u1 & 0xffffu), bf2f(u1 >> 16)};
  *(float4*)(outr + (size_t)gB_ * NN + t * 4) = v;
}

extern "C" void kernel_launch(void* const* d_in, const int* in_sizes, int n_in,
                              void* d_out, int out_size, void* d_ws, size_t ws_size,
                              hipStream_t stream) {
  const float* x    = (const float*)d_in[0];
  const float* DR   = (const float*)d_in[1];
  const float* win  = (const float*)d_in[2];
  const float* bin  = (const float*)d_in[3];
  const float* sw   = (const float*)d_in[4];
  const float* sb   = (const float*)d_in[5];
  const float* n1w  = (const float*)d_in[6];
  const float* n1b  = (const float*)d_in[7];
  const float* n2w  = (const float*)d_in[8];
  const float* n2b  = (const float*)d_in[9];
  const float* wout = (const float*)d_in[10];
  const float* bout = (const float*)d_in[11];
  float* out = (float*)d_out;
  float* W = (float*)d_ws;

  // workspace layout (float offsets)
  unsigned short* drwF  = (unsigned short*)(W);            // 65536 f
  float* t2   = W + 65536;                                 // 512
  float* rcr  = W + 66048;                                 // 512
  float* rclv = W + 66560;                                 // 32768
  float* maxv = W + 99328;                                 // 32768
  unsigned short* drlnF = (unsigned short*)(W + 132096);   // 65536 f
  unsigned short* WoF   = (unsigned short*)(W + 197632);   // 49152 f
  unsigned short* WinF  = (unsigned short*)(W + 246784);   // 49152 f
  unsigned short* semWF = (unsigned short*)(W + 295936);   // 16384 f
  unsigned short* ApF   = (unsigned short*)(W + 312320);   // 4194304 f
  unsigned short* pF    = (unsigned short*)(W + 4506624);  // 8388608 f
  int*   tix  = (int*)(W + 12895232);                      // 648 ints

  float* out_mask = out;
  float* out_img  = out + 32768;
  float* out_res  = out + 32768 + 12582912;

  k_prep   <<<184, 256, 0, stream>>>(DR, n2w, n2b, n1w, n1b, drwF, drlnF, t2, rcr,
                                     win, WinF, sw, semWF, wout, WoF);
  k_convsem<<<1024, 256, 0, stream>>>(x, WinF, bin, semWF, sb, n1w, n1b, ApF, rclv);
  k_sdeg   <<<1024, 256, 0, stream>>>(ApF, drwF, t2, rcr, rclv, drlnF, WoF, bout,
                                      pF, maxv, out_img);
  k_topk   <<<BB,   256, 0, stream>>>(maxv, tix, out_mask);
  k_gather <<<BB * BB * TOPK, 128, 0, stream>>>(pF, tix, out_res);
}